// Round 5
// baseline (908.077 us; speedup 1.0000x reference)
//
#include <hip/hip_runtime.h>

#define D        64
#define BINROWS  64        // rows per bin
#define SEGCAP   1536      // slots per bin segment; mean 1280, sigma ~36 -> +7 sigma
#define NBINS_MAX 1568
#define CHUNK    8192      // edges per expand workgroup

typedef __attribute__((ext_vector_type(8))) short short8;
typedef __attribute__((ext_vector_type(4))) float floatx4;

__device__ __forceinline__ unsigned short f2bf(float f) {
    unsigned u = __float_as_uint(f);
    u += 0x7fffu + ((u >> 16) & 1u);   // RNE
    return (unsigned short)(u >> 16);
}
__device__ __forceinline__ float bf2f(unsigned short u) {
    return __uint_as_float(((unsigned)u) << 16);
}

// ---------------------------------------------------------------------------
// ebs fp32 -> bf16 (12.8 MB table: better L2 residency, half gather bytes)
// ---------------------------------------------------------------------------
__global__ __launch_bounds__(256) void convert_kernel(
    const float* __restrict__ ebs, unsigned short* __restrict__ ebs16, int total4)
{
    int i = blockIdx.x * 256 + threadIdx.x;
    if (i >= total4) return;
    float4 v = ((const float4*)ebs)[i];
    ushort4 o;
    o.x = f2bf(v.x); o.y = f2bf(v.y); o.z = f2bf(v.z); o.w = f2bf(v.w);
    ((ushort4*)ebs16)[i] = o;
}

// ---------------------------------------------------------------------------
// Pack [Ws;Wd] (K=128) into bf16 MFMA B-fragment layout (verified in R3).
// ---------------------------------------------------------------------------
__global__ __launch_bounds__(256) void wfrag_kernel(
    const float* __restrict__ W_side, const float* __restrict__ W_dot,
    unsigned short* __restrict__ Wfrag)
{
    int t = blockIdx.x * 256 + threadIdx.x;   // 0..1023
    int f = t >> 6;                            // fragment 0..15
    int l = t & 63;
    int jt = f >> 2, kt = f & 3;
    int q = l >> 4, nl = l & 15;
    int n = jt * 16 + nl;
#pragma unroll
    for (int j = 0; j < 8; ++j) {
        int k = kt * 32 + q * 8 + j;
        float w = (k < 64) ? W_side[k * 64 + n] : W_dot[(k - 64) * 64 + n];
        Wfrag[(size_t)f * 512 + l * 8 + j] = f2bf(w);
    }
}

// ---------------------------------------------------------------------------
// Expand: LDS-chunked counting-bin scatter (unchanged from R4).
// payload.x = (m<<23)|(rowInBin<<17)|col   payload.y = val bits
// ---------------------------------------------------------------------------
__global__ __launch_bounds__(256) void expand_bin_kernel(
    const int* __restrict__ LI_rows, const int* __restrict__ LI_cols, const float* __restrict__ LI_vals,
    const int* __restrict__ L_rows,  const int* __restrict__ L_cols,  const float* __restrict__ L_vals,
    int* __restrict__ cursor, uint2* __restrict__ seg, int E, int nbins)
{
    __shared__ unsigned int gOf[CHUNK];     // 32 KB: r | (m<<17), 0xFFFFFFFF invalid
    __shared__ int hist[NBINS_MAX];
    __shared__ int cnt2[NBINS_MAX];
    __shared__ int gbase[NBINS_MAX];

    int t = threadIdx.x;
    int c0 = blockIdx.x * CHUNK;
    int twoE = 2 * E;

    for (int b = t; b < nbins; b += 256) { hist[b] = 0; cnt2[b] = 0; }
    __syncthreads();

    // Phase A: read rows, histogram bins
#pragma unroll
    for (int k = 0; k < CHUNK / 256; ++k) {
        int e = c0 + k * 256 + t;
        unsigned g = 0xFFFFFFFFu;
        if (e < twoE) {
            int m = (e >= E) ? 1 : 0;
            int r = m ? L_rows[e - E] : LI_rows[e];
            g = (unsigned)r | ((unsigned)m << 17);
            atomicAdd(&hist[r >> 6], 1);
        }
        gOf[k * 256 + t] = g;
    }
    __syncthreads();

    // Phase B: reserve global runs
    for (int b = t; b < nbins; b += 256) {
        int c = hist[b];
        gbase[b] = c ? atomicAdd(&cursor[b], c) : 0;
    }
    __syncthreads();

    // Phase C: scatter payloads into reserved runs
#pragma unroll
    for (int k = 0; k < CHUNK / 256; ++k) {
        int e = c0 + k * 256 + t;
        unsigned g = gOf[k * 256 + t];
        if (g == 0xFFFFFFFFu) continue;
        int r   = (int)(g & 0x1FFFFu);
        int m   = (int)((g >> 17) & 1u);
        int bin = r >> 6;
        int rib = r & 63;
        int cl; float v;
        if (m) { cl = L_cols[e - E]; v = L_vals[e - E]; }
        else   { cl = LI_cols[e];    v = LI_vals[e]; }
        int rank = atomicAdd(&cnt2[bin], 1);
        int pos  = gbase[bin] + rank;
        if (pos < SEGCAP)
            seg[(size_t)bin * SEGCAP + pos] =
                make_uint2(((unsigned)m << 23) | ((unsigned)rib << 17) | (unsigned)cl,
                           __float_as_uint(v));
    }
}

// ---------------------------------------------------------------------------
// Fused gather + MFMA epilogue. One WG per 64-row bin.
// BUGFIX vs R4: A-fragment reads must index bin-row (w*16 + mcol), not mcol —
// wave w owns rows [w*16, w*16+16) of the bin (store side already did this).
// ---------------------------------------------------------------------------
#define FSTRIDE 68
__global__ __launch_bounds__(256) void fused_kernel(
    const uint2* __restrict__ seg, const int* __restrict__ cursor,
    const unsigned short* __restrict__ ebs16,
    const float* __restrict__ entity,
    const unsigned short* __restrict__ Wfrag,
    float* __restrict__ out, int n)
{
    __shared__ float facc[2 * BINROWS * FSTRIDE];   // 34.8 KB
    int t = threadIdx.x;
    int b = blockIdx.x;

    // zero LDS accumulator (2*64*68 = 8704 floats = 2176 float4)
    float4* fz = (float4*)facc;
    for (int i = t; i < 2 * BINROWS * FSTRIDE / 4; i += 256)
        fz[i] = make_float4(0.f, 0.f, 0.f, 0.f);
    __syncthreads();

    int cnt = cursor[b]; if (cnt > SEGCAP) cnt = SEGCAP;
    const uint2* sp = seg + (size_t)b * SEGCAP;
    int gi = t >> 4, l4 = (t & 15) << 2;

    for (int base = 0; base < cnt; base += 32) {
        int i0 = base + gi;
        int i1 = base + 16 + gi;
        uint2 w0, w1; ushort4 x0, x1;
        bool v0 = i0 < cnt, v1 = i1 < cnt;
        if (v0) { w0 = sp[i0]; x0 = *(const ushort4*)(ebs16 + (size_t)(w0.x & 0x1FFFFu) * D + l4); }
        if (v1) { w1 = sp[i1]; x1 = *(const ushort4*)(ebs16 + (size_t)(w1.x & 0x1FFFFu) * D + l4); }
        if (v0) {
            float v = __uint_as_float(w0.y);
            float* dst = facc + ((w0.x >> 23) * BINROWS + ((w0.x >> 17) & 63u)) * FSTRIDE + l4;
            atomicAdd(dst + 0, v * bf2f(x0.x));
            atomicAdd(dst + 1, v * bf2f(x0.y));
            atomicAdd(dst + 2, v * bf2f(x0.z));
            atomicAdd(dst + 3, v * bf2f(x0.w));
        }
        if (v1) {
            float v = __uint_as_float(w1.y);
            float* dst = facc + ((w1.x >> 23) * BINROWS + ((w1.x >> 17) & 63u)) * FSTRIDE + l4;
            atomicAdd(dst + 0, v * bf2f(x1.x));
            atomicAdd(dst + 1, v * bf2f(x1.y));
            atomicAdd(dst + 2, v * bf2f(x1.z));
            atomicAdd(dst + 3, v * bf2f(x1.w));
        }
    }
    __syncthreads();

    // --- MFMA epilogue: wave w owns bin-rows [w*16, w*16+16) ---
    int w = t >> 6;
    int l = t & 63;
    int q = l >> 4, mcol = l & 15;        // A-row-in-tile == C-col == l&15
    int rowbase = b * BINROWS + w * 16;
    int growA = rowbase + mcol;
    int binrow = w * 16 + mcol;           // row within the bin for this lane's A
    const float* faccLI = facc;
    const float* faccL  = facc + BINROWS * FSTRIDE;

    floatx4 accv[4];
#pragma unroll
    for (int jt = 0; jt < 4; ++jt) accv[jt] = (floatx4){0.f, 0.f, 0.f, 0.f};

#pragma unroll
    for (int kt = 0; kt < 4; ++kt) {
        short8 af;
        if (kt < 2) {
            const float4* ap = (const float4*)(faccLI + binrow * FSTRIDE + kt * 32 + q * 8);
            float4 a0 = ap[0], a1 = ap[1];
            af[0] = (short)f2bf(a0.x); af[1] = (short)f2bf(a0.y);
            af[2] = (short)f2bf(a0.z); af[3] = (short)f2bf(a0.w);
            af[4] = (short)f2bf(a1.x); af[5] = (short)f2bf(a1.y);
            af[6] = (short)f2bf(a1.z); af[7] = (short)f2bf(a1.w);
        } else {
            const float4* lp = (const float4*)(faccL + binrow * FSTRIDE + (kt - 2) * 32 + q * 8);
            float4 l0 = lp[0], l1 = lp[1];
            float4 e0 = make_float4(0.f, 0.f, 0.f, 0.f), e1 = e0;
            if (growA < n) {
                const float4* ep = (const float4*)(entity + (size_t)growA * D + (kt - 2) * 32 + q * 8);
                e0 = ep[0]; e1 = ep[1];
            }
            af[0] = (short)f2bf(l0.x * e0.x); af[1] = (short)f2bf(l0.y * e0.y);
            af[2] = (short)f2bf(l0.z * e0.z); af[3] = (short)f2bf(l0.w * e0.w);
            af[4] = (short)f2bf(l1.x * e1.x); af[5] = (short)f2bf(l1.y * e1.y);
            af[6] = (short)f2bf(l1.z * e1.z); af[7] = (short)f2bf(l1.w * e1.w);
        }
#pragma unroll
        for (int jt = 0; jt < 4; ++jt) {
            const short8 bf = *(const short8*)(Wfrag + (size_t)(jt * 4 + kt) * 512 + (size_t)l * 8);
            accv[jt] = __builtin_amdgcn_mfma_f32_16x16x32_bf16(af, bf, accv[jt], 0, 0, 0);
        }
    }

    // C/D layout: col = l&15, row_in_tile = q*4 + reg (verified R3)
#pragma unroll
    for (int jt = 0; jt < 4; ++jt) {
#pragma unroll
        for (int r = 0; r < 4; ++r) {
            int grow = rowbase + q * 4 + r;
            if (grow < n) {
                float v = accv[jt][r];
                v = v > 0.f ? v : 0.2f * v;
                out[(size_t)grow * D + jt * 16 + mcol] = v;
            }
        }
    }
}

// ---------------------------------------------------------------------------
// Fallback path (only if workspace too small): R1 atomic scatter + fp32 epi.
// ---------------------------------------------------------------------------
__global__ void scatter_kernel(
    const float* __restrict__ LI_vals, const int* __restrict__ LI_rows, const int* __restrict__ LI_cols,
    const float* __restrict__ L_vals,  const int* __restrict__ L_rows,  const int* __restrict__ L_cols,
    const float* __restrict__ ebs,
    float* __restrict__ accLI, float* __restrict__ accL, int E)
{
    long long t = (long long)blockIdx.x * blockDim.x + threadIdx.x;
    long long e2 = t >> 4;
    if (e2 >= 2LL * E) return;
    int c = ((int)t & 15) << 2;
    const float* vals; const int* rows; const int* cols; float* acc; int e;
    if (e2 < E) { vals = LI_vals; rows = LI_rows; cols = LI_cols; acc = accLI; e = (int)e2; }
    else        { vals = L_vals;  rows = L_rows;  cols = L_cols;  acc = accL;  e = (int)(e2 - E); }
    float v = vals[e]; int r = rows[e]; int cl = cols[e];
    const float4 x = *(const float4*)(ebs + (size_t)cl * D + c);
    float* o = acc + (size_t)r * D + c;
    unsafeAtomicAdd(o + 0, v * x.x);
    unsafeAtomicAdd(o + 1, v * x.y);
    unsafeAtomicAdd(o + 2, v * x.z);
    unsafeAtomicAdd(o + 3, v * x.w);
}

__global__ __launch_bounds__(256) void epilogue_kernel(
    const float* __restrict__ acc, const float* __restrict__ entity,
    const float* __restrict__ W_side, const float* __restrict__ W_dot,
    float* __restrict__ out, int n)
{
    int lane = threadIdx.x & 63;
    int wave = (blockIdx.x << 2) | (threadIdx.x >> 6);
    int row  = (wave << 6) + lane;
    bool valid = row < n;
    const float* accLI = acc;
    const float* accL  = acc + (size_t)n * D;
    float a[D], b[D];
    if (valid) {
        const float4* ap = (const float4*)(accLI  + (size_t)row * D);
        const float4* lp = (const float4*)(accL   + (size_t)row * D);
        const float4* ep = (const float4*)(entity + (size_t)row * D);
#pragma unroll
        for (int qq = 0; qq < 16; ++qq) {
            float4 av = ap[qq]; float4 lv = lp[qq]; float4 ev = ep[qq];
            a[4*qq+0] = av.x; a[4*qq+1] = av.y; a[4*qq+2] = av.z; a[4*qq+3] = av.w;
            b[4*qq+0] = lv.x * ev.x; b[4*qq+1] = lv.y * ev.y;
            b[4*qq+2] = lv.z * ev.z; b[4*qq+3] = lv.w * ev.w;
        }
    } else {
#pragma unroll
        for (int qq = 0; qq < D; ++qq) { a[qq] = 0.f; b[qq] = 0.f; }
    }
    float4* op = (float4*)(out + (size_t)row * D);
#pragma unroll 1
    for (int jc = 0; jc < 16; ++jc) {
        float a0 = 0.f, a1 = 0.f, a2 = 0.f, a3 = 0.f;
#pragma unroll
        for (int k = 0; k < D; ++k) {
            float4 w1 = *(const float4*)(W_side + (k << 6) + (jc << 2));
            float4 w2 = *(const float4*)(W_dot  + (k << 6) + (jc << 2));
            a0 += a[k] * w1.x + b[k] * w2.x;
            a1 += a[k] * w1.y + b[k] * w2.y;
            a2 += a[k] * w1.z + b[k] * w2.z;
            a3 += a[k] * w1.w + b[k] * w2.w;
        }
        float4 r;
        r.x = a0 > 0.f ? a0 : 0.2f * a0;
        r.y = a1 > 0.f ? a1 : 0.2f * a1;
        r.z = a2 > 0.f ? a2 : 0.2f * a2;
        r.w = a3 > 0.f ? a3 : 0.2f * a3;
        if (valid) op[jc] = r;
    }
}

extern "C" void kernel_launch(void* const* d_in, const int* in_sizes, int n_in,
                              void* d_out, int out_size, void* d_ws, size_t ws_size,
                              hipStream_t stream) {
    const float* ebs     = (const float*)d_in[0];
    const float* entity  = (const float*)d_in[1];
    const float* W_side  = (const float*)d_in[2];
    const float* W_dot   = (const float*)d_in[3];
    const float* LI_vals = (const float*)d_in[4];
    const float* L_vals  = (const float*)d_in[5];
    const int*   LI_rows = (const int*)d_in[6];
    const int*   LI_cols = (const int*)d_in[7];
    const int*   L_rows  = (const int*)d_in[8];
    const int*   L_cols  = (const int*)d_in[9];
    float* out = (float*)d_out;

    int E = in_sizes[4];
    int n = in_sizes[0] / D;
    int nbins = (n + BINROWS - 1) / BINROWS;

    size_t curBytes = (size_t)NBINS_MAX * sizeof(int);                  // 6.3 KB
    size_t segBytes = (size_t)nbins * SEGCAP * sizeof(uint2);           // 19.2 MB
    size_t ebsBytes = (size_t)n * D * sizeof(unsigned short);           // 12.8 MB
    size_t wfBytes  = (size_t)16 * 512 * sizeof(unsigned short);        // 16 KB
    size_t need = curBytes + segBytes + ebsBytes + wfBytes;

    if (ws_size >= need && nbins <= NBINS_MAX && n <= 131072) {
        int*            cursor = (int*)d_ws;
        uint2*          seg    = (uint2*)((char*)d_ws + curBytes);
        unsigned short* ebs16  = (unsigned short*)((char*)d_ws + curBytes + segBytes);
        unsigned short* Wfrag  = (unsigned short*)((char*)d_ws + curBytes + segBytes + ebsBytes);

        hipMemsetAsync(cursor, 0, curBytes, stream);

        int total4 = n * D / 4;
        convert_kernel<<<(total4 + 255) / 256, 256, 0, stream>>>(ebs, ebs16, total4);
        wfrag_kernel<<<4, 256, 0, stream>>>(W_side, W_dot, Wfrag);

        int xblocks = (2 * E + CHUNK - 1) / CHUNK;
        expand_bin_kernel<<<xblocks, 256, 0, stream>>>(
            LI_rows, LI_cols, LI_vals, L_rows, L_cols, L_vals,
            cursor, seg, E, nbins);

        fused_kernel<<<nbins, 256, 0, stream>>>(
            seg, cursor, ebs16, entity, Wfrag, out, n);
    } else {
        size_t accBytes = (size_t)2 * n * D * sizeof(float);
        float* acc   = (float*)d_ws;
        float* accLI = acc;
        float* accL  = accLI + (size_t)n * D;
        hipMemsetAsync(d_ws, 0, accBytes, stream);
        long long totalThreads = 2LL * E * 16;
        int sblocks = (int)((totalThreads + 255) / 256);
        scatter_kernel<<<sblocks, 256, 0, stream>>>(
            LI_vals, LI_rows, LI_cols, L_vals, L_rows, L_cols, ebs, accLI, accL, E);
        int nTiles = (n + 63) / 64;
        epilogue_kernel<<<(nTiles + 3) / 4, 256, 0, stream>>>(
            acc, entity, W_side, W_dot, out, n);
    }
}

// Round 6
// 343.727 us; speedup vs baseline: 2.6419x; 2.6419x over previous
//
#include <hip/hip_runtime.h>

#define D        64
#define BINROWS  64        // rows per bin
#define SEGCAP   1536      // slots per bin segment; mean 1280 -> +7 sigma
#define NBINS_MAX 1568
#define CHUNK    4096      // edges per expand workgroup (smaller -> more TLP)
#define FSTRIDE  68        // facc row stride in floats

typedef __attribute__((ext_vector_type(8))) short short8;
typedef __attribute__((ext_vector_type(4))) float floatx4;

__device__ __forceinline__ unsigned short f2bf(float f) {
    unsigned u = __float_as_uint(f);
    u += 0x7fffu + ((u >> 16) & 1u);   // RNE
    return (unsigned short)(u >> 16);
}
__device__ __forceinline__ float bf2f(unsigned short u) {
    return __uint_as_float(((unsigned)u) << 16);
}

// ---------------------------------------------------------------------------
// ebs fp32 -> bf16
// ---------------------------------------------------------------------------
__global__ __launch_bounds__(256) void convert_kernel(
    const float* __restrict__ ebs, unsigned short* __restrict__ ebs16, int total4)
{
    int i = blockIdx.x * 256 + threadIdx.x;
    if (i >= total4) return;
    float4 v = ((const float4*)ebs)[i];
    ushort4 o;
    o.x = f2bf(v.x); o.y = f2bf(v.y); o.z = f2bf(v.z); o.w = f2bf(v.w);
    ((ushort4*)ebs16)[i] = o;
}

// ---------------------------------------------------------------------------
// Pack [Ws;Wd] (K=128) into bf16 MFMA B-fragment layout (verified R3).
// ---------------------------------------------------------------------------
__global__ __launch_bounds__(256) void wfrag_kernel(
    const float* __restrict__ W_side, const float* __restrict__ W_dot,
    unsigned short* __restrict__ Wfrag)
{
    int t = blockIdx.x * 256 + threadIdx.x;   // 0..1023
    int f = t >> 6;                            // fragment 0..15
    int l = t & 63;
    int jt = f >> 2, kt = f & 3;
    int q = l >> 4, nl = l & 15;
    int n = jt * 16 + nl;
#pragma unroll
    for (int j = 0; j < 8; ++j) {
        int k = kt * 32 + q * 8 + j;
        float w = (k < 64) ? W_side[k * 64 + n] : W_dot[(k - 64) * 64 + n];
        Wfrag[(size_t)f * 512 + l * 8 + j] = f2bf(w);
    }
}

// ---------------------------------------------------------------------------
// Expand: LDS-chunked counting-bin scatter (CHUNK 4096 for occupancy).
// payload.x = (m<<23)|(rowInBin<<17)|col   payload.y = val bits
// ---------------------------------------------------------------------------
__global__ __launch_bounds__(256) void expand_bin_kernel(
    const int* __restrict__ LI_rows, const int* __restrict__ LI_cols, const float* __restrict__ LI_vals,
    const int* __restrict__ L_rows,  const int* __restrict__ L_cols,  const float* __restrict__ L_vals,
    int* __restrict__ cursor, uint2* __restrict__ seg, int E, int nbins)
{
    __shared__ unsigned int gOf[CHUNK];     // 16 KB: r | (m<<17), 0xFFFFFFFF invalid
    __shared__ int hist[NBINS_MAX];
    __shared__ int cnt2[NBINS_MAX];
    __shared__ int gbase[NBINS_MAX];

    int t = threadIdx.x;
    int c0 = blockIdx.x * CHUNK;
    int twoE = 2 * E;

    for (int b = t; b < nbins; b += 256) { hist[b] = 0; cnt2[b] = 0; }
    __syncthreads();

    // Phase A: read rows, histogram bins
#pragma unroll
    for (int k = 0; k < CHUNK / 256; ++k) {
        int e = c0 + k * 256 + t;
        unsigned g = 0xFFFFFFFFu;
        if (e < twoE) {
            int m = (e >= E) ? 1 : 0;
            int r = m ? L_rows[e - E] : LI_rows[e];
            g = (unsigned)r | ((unsigned)m << 17);
            atomicAdd(&hist[r >> 6], 1);
        }
        gOf[k * 256 + t] = g;
    }
    __syncthreads();

    // Phase B: reserve global runs
    for (int b = t; b < nbins; b += 256) {
        int c = hist[b];
        gbase[b] = c ? atomicAdd(&cursor[b], c) : 0;
    }
    __syncthreads();

    // Phase C: scatter payloads into reserved runs
#pragma unroll
    for (int k = 0; k < CHUNK / 256; ++k) {
        int e = c0 + k * 256 + t;
        unsigned g = gOf[k * 256 + t];
        if (g == 0xFFFFFFFFu) continue;
        int r   = (int)(g & 0x1FFFFu);
        int m   = (int)((g >> 17) & 1u);
        int bin = r >> 6;
        int rib = r & 63;
        int cl; float v;
        if (m) { cl = L_cols[e - E]; v = L_vals[e - E]; }
        else   { cl = LI_cols[e];    v = LI_vals[e]; }
        int rank = atomicAdd(&cnt2[bin], 1);
        int pos  = gbase[bin] + rank;
        if (pos < SEGCAP)
            seg[(size_t)bin * SEGCAP + pos] =
                make_uint2(((unsigned)m << 23) | ((unsigned)rib << 17) | (unsigned)cl,
                           __float_as_uint(v));
    }
}

// ---------------------------------------------------------------------------
// Fused kernel v2: counting-sort by (m,rib) key, row-owned register
// accumulation (NO fp32 LDS atomics), plain LDS writes, MFMA epilogue.
// One WG per 64-row bin; 16 groups of 16 lanes; group g owns keys
// [g*8, g*8+8) -> 8 independent gather chains for ILP.
// ---------------------------------------------------------------------------
__global__ __launch_bounds__(256) void fused_kernel(
    const uint2* __restrict__ seg, const int* __restrict__ cursor,
    const unsigned short* __restrict__ ebs16,
    const float* __restrict__ entity,
    const unsigned short* __restrict__ Wfrag,
    float* __restrict__ out, int n)
{
    __shared__ unsigned short sidx[SEGCAP];          // 3 KB sorted entry indices
    __shared__ int hist[128];
    __shared__ int offs[128];
    __shared__ int cur[128];
    __shared__ float facc[2 * BINROWS * FSTRIDE];    // 34816 B
    int t = threadIdx.x;
    int b = blockIdx.x;

    if (t < 128) hist[t] = 0;
    __syncthreads();

    int cnt = cursor[b]; if (cnt > SEGCAP) cnt = SEGCAP;
    const uint2* sp = seg + (size_t)b * SEGCAP;

    // Pass 1: histogram of 7-bit keys (int LDS atomics -- ds_add_u32, fast)
    for (int i = t; i < cnt; i += 256) {
        unsigned key = (sp[i].x >> 17) & 127u;
        atomicAdd(&hist[key], 1);
    }
    __syncthreads();

    // Exclusive scan over 128 (Hillis-Steele)
    if (t < 128) offs[t] = hist[t];
    __syncthreads();
    for (int step = 1; step < 128; step <<= 1) {
        int add = 0;
        if (t < 128 && t >= step) add = offs[t - step];
        __syncthreads();
        if (t < 128) offs[t] += add;
        __syncthreads();
    }
    if (t < 128) {
        int excl = offs[t] - hist[t];
        offs[t] = excl;
        cur[t]  = excl;
    }
    __syncthreads();

    // Pass 2: rank + write sorted index
    for (int i = t; i < cnt; i += 256) {
        unsigned key = (sp[i].x >> 17) & 127u;
        int rank = atomicAdd(&cur[key], 1);
        sidx[rank] = (unsigned short)i;
    }
    __syncthreads();

    // Accumulate: group g owns keys [g*8, g*8+8); slot-major loop gives
    // 8 independent gather chains in flight per lane.
    int g  = t >> 4;
    int l4 = (t & 15) << 2;
    int beg[8], len[8];
    int maxlen = 0;
#pragma unroll
    for (int kk = 0; kk < 8; ++kk) {
        int key = g * 8 + kk;
        beg[kk] = offs[key];
        len[kk] = hist[key];
        maxlen = max(maxlen, len[kk]);
    }
    floatx4 a8[8];
#pragma unroll
    for (int kk = 0; kk < 8; ++kk) a8[kk] = (floatx4){0.f, 0.f, 0.f, 0.f};

    for (int s = 0; s < maxlen; ++s) {
#pragma unroll
        for (int kk = 0; kk < 8; ++kk) {
            if (s < len[kk]) {                         // group-uniform branch
                int idx = sidx[beg[kk] + s];
                uint2 en = sp[idx];                    // 8 B, L2-hot
                float vv = __uint_as_float(en.y);
                ushort4 x = *(const ushort4*)(ebs16 + (size_t)(en.x & 0x1FFFFu) * D + l4);
                a8[kk][0] += vv * bf2f(x.x);
                a8[kk][1] += vv * bf2f(x.y);
                a8[kk][2] += vv * bf2f(x.z);
                a8[kk][3] += vv * bf2f(x.w);
            }
        }
    }
#pragma unroll
    for (int kk = 0; kk < 8; ++kk) {
        int key = g * 8 + kk;
        float* dst = facc + (key >> 6) * (BINROWS * FSTRIDE) + (key & 63) * FSTRIDE + l4;
        *(float4*)dst = make_float4(a8[kk][0], a8[kk][1], a8[kk][2], a8[kk][3]);
    }
    __syncthreads();

    // --- MFMA epilogue: wave w owns bin-rows [w*16, w*16+16) (verified R5) ---
    int w = t >> 6;
    int l = t & 63;
    int q = l >> 4, mcol = l & 15;
    int rowbase = b * BINROWS + w * 16;
    int growA = rowbase + mcol;
    int binrow = w * 16 + mcol;
    const float* faccLI = facc;
    const float* faccL  = facc + BINROWS * FSTRIDE;

    floatx4 accv[4];
#pragma unroll
    for (int jt = 0; jt < 4; ++jt) accv[jt] = (floatx4){0.f, 0.f, 0.f, 0.f};

#pragma unroll
    for (int kt = 0; kt < 4; ++kt) {
        short8 af;
        if (kt < 2) {
            const float4* ap = (const float4*)(faccLI + binrow * FSTRIDE + kt * 32 + q * 8);
            float4 a0 = ap[0], a1 = ap[1];
            af[0] = (short)f2bf(a0.x); af[1] = (short)f2bf(a0.y);
            af[2] = (short)f2bf(a0.z); af[3] = (short)f2bf(a0.w);
            af[4] = (short)f2bf(a1.x); af[5] = (short)f2bf(a1.y);
            af[6] = (short)f2bf(a1.z); af[7] = (short)f2bf(a1.w);
        } else {
            const float4* lp = (const float4*)(faccL + binrow * FSTRIDE + (kt - 2) * 32 + q * 8);
            float4 l0 = lp[0], l1 = lp[1];
            float4 e0 = make_float4(0.f, 0.f, 0.f, 0.f), e1 = e0;
            if (growA < n) {
                const float4* ep = (const float4*)(entity + (size_t)growA * D + (kt - 2) * 32 + q * 8);
                e0 = ep[0]; e1 = ep[1];
            }
            af[0] = (short)f2bf(l0.x * e0.x); af[1] = (short)f2bf(l0.y * e0.y);
            af[2] = (short)f2bf(l0.z * e0.z); af[3] = (short)f2bf(l0.w * e0.w);
            af[4] = (short)f2bf(l1.x * e1.x); af[5] = (short)f2bf(l1.y * e1.y);
            af[6] = (short)f2bf(l1.z * e1.z); af[7] = (short)f2bf(l1.w * e1.w);
        }
#pragma unroll
        for (int jt = 0; jt < 4; ++jt) {
            const short8 bf = *(const short8*)(Wfrag + (size_t)(jt * 4 + kt) * 512 + (size_t)l * 8);
            accv[jt] = __builtin_amdgcn_mfma_f32_16x16x32_bf16(af, bf, accv[jt], 0, 0, 0);
        }
    }

#pragma unroll
    for (int jt = 0; jt < 4; ++jt) {
#pragma unroll
        for (int r = 0; r < 4; ++r) {
            int grow = rowbase + q * 4 + r;
            if (grow < n) {
                float v = accv[jt][r];
                v = v > 0.f ? v : 0.2f * v;
                out[(size_t)grow * D + jt * 16 + mcol] = v;
            }
        }
    }
}

// ---------------------------------------------------------------------------
// Fallback path (only if workspace too small): R1 atomic scatter + fp32 epi.
// ---------------------------------------------------------------------------
__global__ void scatter_kernel(
    const float* __restrict__ LI_vals, const int* __restrict__ LI_rows, const int* __restrict__ LI_cols,
    const float* __restrict__ L_vals,  const int* __restrict__ L_rows,  const int* __restrict__ L_cols,
    const float* __restrict__ ebs,
    float* __restrict__ accLI, float* __restrict__ accL, int E)
{
    long long t = (long long)blockIdx.x * blockDim.x + threadIdx.x;
    long long e2 = t >> 4;
    if (e2 >= 2LL * E) return;
    int c = ((int)t & 15) << 2;
    const float* vals; const int* rows; const int* cols; float* acc; int e;
    if (e2 < E) { vals = LI_vals; rows = LI_rows; cols = LI_cols; acc = accLI; e = (int)e2; }
    else        { vals = L_vals;  rows = L_rows;  cols = L_cols;  acc = accL;  e = (int)(e2 - E); }
    float v = vals[e]; int r = rows[e]; int cl = cols[e];
    const float4 x = *(const float4*)(ebs + (size_t)cl * D + c);
    float* o = acc + (size_t)r * D + c;
    unsafeAtomicAdd(o + 0, v * x.x);
    unsafeAtomicAdd(o + 1, v * x.y);
    unsafeAtomicAdd(o + 2, v * x.z);
    unsafeAtomicAdd(o + 3, v * x.w);
}

__global__ __launch_bounds__(256) void epilogue_kernel(
    const float* __restrict__ acc, const float* __restrict__ entity,
    const float* __restrict__ W_side, const float* __restrict__ W_dot,
    float* __restrict__ out, int n)
{
    int lane = threadIdx.x & 63;
    int wave = (blockIdx.x << 2) | (threadIdx.x >> 6);
    int row  = (wave << 6) + lane;
    bool valid = row < n;
    const float* accLI = acc;
    const float* accL  = acc + (size_t)n * D;
    float a[D], b[D];
    if (valid) {
        const float4* ap = (const float4*)(accLI  + (size_t)row * D);
        const float4* lp = (const float4*)(accL   + (size_t)row * D);
        const float4* ep = (const float4*)(entity + (size_t)row * D);
#pragma unroll
        for (int qq = 0; qq < 16; ++qq) {
            float4 av = ap[qq]; float4 lv = lp[qq]; float4 ev = ep[qq];
            a[4*qq+0] = av.x; a[4*qq+1] = av.y; a[4*qq+2] = av.z; a[4*qq+3] = av.w;
            b[4*qq+0] = lv.x * ev.x; b[4*qq+1] = lv.y * ev.y;
            b[4*qq+2] = lv.z * ev.z; b[4*qq+3] = lv.w * ev.w;
        }
    } else {
#pragma unroll
        for (int qq = 0; qq < D; ++qq) { a[qq] = 0.f; b[qq] = 0.f; }
    }
    float4* op = (float4*)(out + (size_t)row * D);
#pragma unroll 1
    for (int jc = 0; jc < 16; ++jc) {
        float a0 = 0.f, a1 = 0.f, a2 = 0.f, a3 = 0.f;
#pragma unroll
        for (int k = 0; k < D; ++k) {
            float4 w1 = *(const float4*)(W_side + (k << 6) + (jc << 2));
            float4 w2 = *(const float4*)(W_dot  + (k << 6) + (jc << 2));
            a0 += a[k] * w1.x + b[k] * w2.x;
            a1 += a[k] * w1.y + b[k] * w2.y;
            a2 += a[k] * w1.z + b[k] * w2.z;
            a3 += a[k] * w1.w + b[k] * w2.w;
        }
        float4 r;
        r.x = a0 > 0.f ? a0 : 0.2f * a0;
        r.y = a1 > 0.f ? a1 : 0.2f * a1;
        r.z = a2 > 0.f ? a2 : 0.2f * a2;
        r.w = a3 > 0.f ? a3 : 0.2f * a3;
        if (valid) op[jc] = r;
    }
}

extern "C" void kernel_launch(void* const* d_in, const int* in_sizes, int n_in,
                              void* d_out, int out_size, void* d_ws, size_t ws_size,
                              hipStream_t stream) {
    const float* ebs     = (const float*)d_in[0];
    const float* entity  = (const float*)d_in[1];
    const float* W_side  = (const float*)d_in[2];
    const float* W_dot   = (const float*)d_in[3];
    const float* LI_vals = (const float*)d_in[4];
    const float* L_vals  = (const float*)d_in[5];
    const int*   LI_rows = (const int*)d_in[6];
    const int*   LI_cols = (const int*)d_in[7];
    const int*   L_rows  = (const int*)d_in[8];
    const int*   L_cols  = (const int*)d_in[9];
    float* out = (float*)d_out;

    int E = in_sizes[4];
    int n = in_sizes[0] / D;
    int nbins = (n + BINROWS - 1) / BINROWS;

    size_t curBytes = (size_t)NBINS_MAX * sizeof(int);                  // 6.3 KB
    size_t segBytes = (size_t)nbins * SEGCAP * sizeof(uint2);           // 19.2 MB
    size_t ebsBytes = (size_t)n * D * sizeof(unsigned short);           // 12.8 MB
    size_t wfBytes  = (size_t)16 * 512 * sizeof(unsigned short);        // 16 KB
    size_t need = curBytes + segBytes + ebsBytes + wfBytes;

    if (ws_size >= need && nbins <= NBINS_MAX && n <= 131072) {
        int*            cursor = (int*)d_ws;
        uint2*          seg    = (uint2*)((char*)d_ws + curBytes);
        unsigned short* ebs16  = (unsigned short*)((char*)d_ws + curBytes + segBytes);
        unsigned short* Wfrag  = (unsigned short*)((char*)d_ws + curBytes + segBytes + ebsBytes);

        hipMemsetAsync(cursor, 0, curBytes, stream);

        int total4 = n * D / 4;
        convert_kernel<<<(total4 + 255) / 256, 256, 0, stream>>>(ebs, ebs16, total4);
        wfrag_kernel<<<4, 256, 0, stream>>>(W_side, W_dot, Wfrag);

        int xblocks = (2 * E + CHUNK - 1) / CHUNK;
        expand_bin_kernel<<<xblocks, 256, 0, stream>>>(
            LI_rows, LI_cols, LI_vals, L_rows, L_cols, L_vals,
            cursor, seg, E, nbins);

        fused_kernel<<<nbins, 256, 0, stream>>>(
            seg, cursor, ebs16, entity, Wfrag, out, n);
    } else {
        size_t accBytes = (size_t)2 * n * D * sizeof(float);
        float* acc   = (float*)d_ws;
        float* accLI = acc;
        float* accL  = accLI + (size_t)n * D;
        hipMemsetAsync(d_ws, 0, accBytes, stream);
        long long totalThreads = 2LL * E * 16;
        int sblocks = (int)((totalThreads + 255) / 256);
        scatter_kernel<<<sblocks, 256, 0, stream>>>(
            LI_vals, LI_rows, LI_cols, L_vals, L_rows, L_cols, ebs, accLI, accL, E);
        int nTiles = (n + 63) / 64;
        epilogue_kernel<<<(nTiles + 3) / 4, 256, 0, stream>>>(
            acc, entity, W_side, W_dot, out, n);
    }
}

// Round 7
// 272.608 us; speedup vs baseline: 3.3311x; 1.2609x over previous
//
#include <hip/hip_runtime.h>

#define D        64
#define BINROWS  64         // rows per bin
#define SUBCAP   256        // slots per (shard,bin): mean 160, sigma 12 -> +8 sigma
#define NSHARD   8
#define NBINS_MAX 1568
#define CHUNK    4096       // edges per expand workgroup
#define FSTRIDE  68         // facc row stride in floats
#define SSEGCAP  2048       // sorted-entry LDS capacity (8*SUBCAP)
#define CURSTRIDE 16        // ints per cursor (64 B padding -> own cache line)

typedef __attribute__((ext_vector_type(8))) short short8;
typedef __attribute__((ext_vector_type(4))) float floatx4;

__device__ __forceinline__ unsigned short f2bf(float f) {
    unsigned u = __float_as_uint(f);
    u += 0x7fffu + ((u >> 16) & 1u);   // RNE
    return (unsigned short)(u >> 16);
}
__device__ __forceinline__ float bf2f(unsigned short u) {
    return __uint_as_float(((unsigned)u) << 16);
}

// ---------------------------------------------------------------------------
// ebs fp32 -> bf16
// ---------------------------------------------------------------------------
__global__ __launch_bounds__(256) void convert_kernel(
    const float* __restrict__ ebs, unsigned short* __restrict__ ebs16, int total4)
{
    int i = blockIdx.x * 256 + threadIdx.x;
    if (i >= total4) return;
    float4 v = ((const float4*)ebs)[i];
    ushort4 o;
    o.x = f2bf(v.x); o.y = f2bf(v.y); o.z = f2bf(v.z); o.w = f2bf(v.w);
    ((ushort4*)ebs16)[i] = o;
}

// ---------------------------------------------------------------------------
// Pack [Ws;Wd] (K=128) into bf16 MFMA B-fragment layout (verified R3).
// ---------------------------------------------------------------------------
__global__ __launch_bounds__(256) void wfrag_kernel(
    const float* __restrict__ W_side, const float* __restrict__ W_dot,
    unsigned short* __restrict__ Wfrag)
{
    int t = blockIdx.x * 256 + threadIdx.x;   // 0..1023
    int f = t >> 6;
    int l = t & 63;
    int jt = f >> 2, kt = f & 3;
    int q = l >> 4, nl = l & 15;
    int n = jt * 16 + nl;
#pragma unroll
    for (int j = 0; j < 8; ++j) {
        int k = kt * 32 + q * 8 + j;
        float w = (k < 64) ? W_side[k * 64 + n] : W_dot[(k - 64) * 64 + n];
        Wfrag[(size_t)f * 512 + l * 8 + j] = f2bf(w);
    }
}

// ---------------------------------------------------------------------------
// Expand v3: edges -> per-(shard,bin) sub-segments.
//  - (col,val,row) held in registers from phase A (no re-read, no gOf LDS)
//  - cursors sharded by blockIdx&7 and padded to 64 B: ~61 same-address
//    atomics per cursor instead of 489 same-line x16.
// payload.x = (m<<23)|(rowInBin<<17)|col   payload.y = val bits
// ---------------------------------------------------------------------------
__global__ __launch_bounds__(256) void expand_bin_kernel(
    const int* __restrict__ LI_rows, const int* __restrict__ LI_cols, const float* __restrict__ LI_vals,
    const int* __restrict__ L_rows,  const int* __restrict__ L_cols,  const float* __restrict__ L_vals,
    int* __restrict__ cursorP, uint2* __restrict__ seg, int E, int nbins)
{
    __shared__ int hist[NBINS_MAX];
    __shared__ int cnt2[NBINS_MAX];
    __shared__ int gbase[NBINS_MAX];

    int t  = threadIdx.x;
    int c0 = blockIdx.x * CHUNK;
    int sh = blockIdx.x & (NSHARD - 1);
    int twoE = 2 * E;

    for (int b = t; b < nbins; b += 256) { hist[b] = 0; cnt2[b] = 0; }
    __syncthreads();

    unsigned rm[CHUNK / 256];
    uint2    cv[CHUNK / 256];

    // Phase A: read rows+cols+vals into registers, LDS histogram of bins
#pragma unroll
    for (int k = 0; k < CHUNK / 256; ++k) {
        int e = c0 + k * 256 + t;
        rm[k] = 0xFFFFFFFFu;
        if (e < twoE) {
            int m = (e >= E) ? 1 : 0;
            int r, cl; float v;
            if (m) { r = L_rows[e - E]; cl = L_cols[e - E]; v = L_vals[e - E]; }
            else   { r = LI_rows[e];    cl = LI_cols[e];    v = LI_vals[e]; }
            rm[k] = (unsigned)r | ((unsigned)m << 17);
            cv[k] = make_uint2((unsigned)cl, __float_as_uint(v));
            atomicAdd(&hist[r >> 6], 1);
        }
    }
    __syncthreads();

    // Phase B: reserve runs in this WG's shard (padded cursors)
    for (int b = t; b < nbins; b += 256) {
        int c = hist[b];
        gbase[b] = c ? atomicAdd(&cursorP[(sh * NBINS_MAX + b) * CURSTRIDE], c) : 0;
    }
    __syncthreads();

    // Phase C: scatter payloads (registers -> global), LDS rank atomics only
#pragma unroll
    for (int k = 0; k < CHUNK / 256; ++k) {
        unsigned g = rm[k];
        if (g == 0xFFFFFFFFu) continue;
        int r   = (int)(g & 0x1FFFFu);
        int m   = (int)((g >> 17) & 1u);
        int bin = r >> 6;
        int rib = r & 63;
        int rank = atomicAdd(&cnt2[bin], 1);
        int pos  = gbase[bin] + rank;
        if (pos < SUBCAP)
            seg[((size_t)(sh * NBINS_MAX) + bin) * SUBCAP + pos] =
                make_uint2(((unsigned)m << 23) | ((unsigned)rib << 17) | cv[k].x, cv[k].y);
    }
}

// ---------------------------------------------------------------------------
// Fused v3: read 8 sub-segments (held in registers), counting-sort the
// VALUES into LDS (unioned with facc), 2-hop accumulate
// (ds_read_b64 broadcast -> gather), plain LDS facc writes, MFMA epilogue.
// ---------------------------------------------------------------------------
__global__ __launch_bounds__(256) void fused_kernel(
    const uint2* __restrict__ seg, const int* __restrict__ cursorP,
    const unsigned short* __restrict__ ebs16,
    const float* __restrict__ entity,
    const unsigned short* __restrict__ Wfrag,
    float* __restrict__ out, int n)
{
    __shared__ __align__(16) char shmem[2 * BINROWS * FSTRIDE * 4];  // 34816 B
    __shared__ int hist[128];
    __shared__ int offs[128];
    __shared__ int cur[128];
    uint2* sseg = (uint2*)shmem;          // sorted entries (<= SSEGCAP*8 = 16 KB)
    float* facc = (float*)shmem;          // reused after accumulate barrier

    int t = threadIdx.x;
    int b = blockIdx.x;

    if (t < 128) hist[t] = 0;
    __syncthreads();

    // Load per-shard counts + this thread's entries (<=1 per shard since SUBCAP<=256)
    int clen[NSHARD];
    uint2 held[NSHARD];
    unsigned hmask = 0;
#pragma unroll
    for (int sh = 0; sh < NSHARD; ++sh) {
        int c = cursorP[(sh * NBINS_MAX + b) * CURSTRIDE];
        clen[sh] = c < SUBCAP ? c : SUBCAP;
        if (t < clen[sh]) {
            held[sh] = seg[((size_t)(sh * NBINS_MAX) + b) * SUBCAP + t];
            hmask |= (1u << sh);
            atomicAdd(&hist[(held[sh].x >> 17) & 127u], 1);
        }
    }
    __syncthreads();

    // Exclusive scan over 128 keys (Hillis-Steele)
    if (t < 128) offs[t] = hist[t];
    __syncthreads();
    for (int step = 1; step < 128; step <<= 1) {
        int add = 0;
        if (t < 128 && t >= step) add = offs[t - step];
        __syncthreads();
        if (t < 128) offs[t] += add;
        __syncthreads();
    }
    if (t < 128) {
        int excl = offs[t] - hist[t];
        offs[t] = excl;
        cur[t]  = excl;
    }
    __syncthreads();

    // Scatter held entries into sorted LDS array
#pragma unroll
    for (int sh = 0; sh < NSHARD; ++sh) {
        if (hmask & (1u << sh)) {
            unsigned key = (held[sh].x >> 17) & 127u;
            int rank = atomicAdd(&cur[key], 1);
            sseg[rank] = held[sh];
        }
    }
    __syncthreads();

    // Accumulate: group g (16 lanes) owns keys [g*8, g*8+8) -> 8 chains.
    int g  = t >> 4;
    int l4 = (t & 15) << 2;
    int beg[8], len[8];
    int maxlen = 0;
#pragma unroll
    for (int kk = 0; kk < 8; ++kk) {
        int key = g * 8 + kk;
        beg[kk] = offs[key];
        len[kk] = hist[key];
        maxlen = max(maxlen, len[kk]);
    }
    floatx4 a8[8];
#pragma unroll
    for (int kk = 0; kk < 8; ++kk) a8[kk] = (floatx4){0.f, 0.f, 0.f, 0.f};

    for (int s = 0; s < maxlen; ++s) {
#pragma unroll
        for (int kk = 0; kk < 8; ++kk) {
            if (s < len[kk]) {                       // group-uniform branch
                uint2 en = sseg[beg[kk] + s];        // LDS broadcast, 2-way free
                float vv = __uint_as_float(en.y);
                ushort4 x = *(const ushort4*)(ebs16 + (size_t)(en.x & 0x1FFFFu) * D + l4);
                a8[kk][0] += vv * bf2f(x.x);
                a8[kk][1] += vv * bf2f(x.y);
                a8[kk][2] += vv * bf2f(x.z);
                a8[kk][3] += vv * bf2f(x.w);
            }
        }
    }
    __syncthreads();   // all sseg reads done before facc overwrites the union

#pragma unroll
    for (int kk = 0; kk < 8; ++kk) {
        int key = g * 8 + kk;
        float* dst = facc + ((key >> 6) * BINROWS + (key & 63)) * FSTRIDE + l4;
        *(float4*)dst = make_float4(a8[kk][0], a8[kk][1], a8[kk][2], a8[kk][3]);
    }
    __syncthreads();

    // --- MFMA epilogue (verified R5/R6): wave w owns bin-rows [w*16,+16) ---
    int w = t >> 6;
    int l = t & 63;
    int q = l >> 4, mcol = l & 15;
    int rowbase = b * BINROWS + w * 16;
    int growA = rowbase + mcol;
    int binrow = w * 16 + mcol;
    const float* faccLI = facc;
    const float* faccL  = facc + BINROWS * FSTRIDE;

    floatx4 accv[4];
#pragma unroll
    for (int jt = 0; jt < 4; ++jt) accv[jt] = (floatx4){0.f, 0.f, 0.f, 0.f};

#pragma unroll
    for (int kt = 0; kt < 4; ++kt) {
        short8 af;
        if (kt < 2) {
            const float4* ap = (const float4*)(faccLI + binrow * FSTRIDE + kt * 32 + q * 8);
            float4 a0 = ap[0], a1 = ap[1];
            af[0] = (short)f2bf(a0.x); af[1] = (short)f2bf(a0.y);
            af[2] = (short)f2bf(a0.z); af[3] = (short)f2bf(a0.w);
            af[4] = (short)f2bf(a1.x); af[5] = (short)f2bf(a1.y);
            af[6] = (short)f2bf(a1.z); af[7] = (short)f2bf(a1.w);
        } else {
            const float4* lp = (const float4*)(faccL + binrow * FSTRIDE + (kt - 2) * 32 + q * 8);
            float4 l0 = lp[0], l1 = lp[1];
            float4 e0 = make_float4(0.f, 0.f, 0.f, 0.f), e1 = e0;
            if (growA < n) {
                const float4* ep = (const float4*)(entity + (size_t)growA * D + (kt - 2) * 32 + q * 8);
                e0 = ep[0]; e1 = ep[1];
            }
            af[0] = (short)f2bf(l0.x * e0.x); af[1] = (short)f2bf(l0.y * e0.y);
            af[2] = (short)f2bf(l0.z * e0.z); af[3] = (short)f2bf(l0.w * e0.w);
            af[4] = (short)f2bf(l1.x * e1.x); af[5] = (short)f2bf(l1.y * e1.y);
            af[6] = (short)f2bf(l1.z * e1.z); af[7] = (short)f2bf(l1.w * e1.w);
        }
#pragma unroll
        for (int jt = 0; jt < 4; ++jt) {
            const short8 bf = *(const short8*)(Wfrag + (size_t)(jt * 4 + kt) * 512 + (size_t)l * 8);
            accv[jt] = __builtin_amdgcn_mfma_f32_16x16x32_bf16(af, bf, accv[jt], 0, 0, 0);
        }
    }

#pragma unroll
    for (int jt = 0; jt < 4; ++jt) {
#pragma unroll
        for (int r = 0; r < 4; ++r) {
            int grow = rowbase + q * 4 + r;
            if (grow < n) {
                float v = accv[jt][r];
                v = v > 0.f ? v : 0.2f * v;
                out[(size_t)grow * D + jt * 16 + mcol] = v;
            }
        }
    }
}

// ---------------------------------------------------------------------------
// Fallback path (only if workspace too small): R1 atomic scatter + fp32 epi.
// ---------------------------------------------------------------------------
__global__ void scatter_kernel(
    const float* __restrict__ LI_vals, const int* __restrict__ LI_rows, const int* __restrict__ LI_cols,
    const float* __restrict__ L_vals,  const int* __restrict__ L_rows,  const int* __restrict__ L_cols,
    const float* __restrict__ ebs,
    float* __restrict__ accLI, float* __restrict__ accL, int E)
{
    long long t = (long long)blockIdx.x * blockDim.x + threadIdx.x;
    long long e2 = t >> 4;
    if (e2 >= 2LL * E) return;
    int c = ((int)t & 15) << 2;
    const float* vals; const int* rows; const int* cols; float* acc; int e;
    if (e2 < E) { vals = LI_vals; rows = LI_rows; cols = LI_cols; acc = accLI; e = (int)e2; }
    else        { vals = L_vals;  rows = L_rows;  cols = L_cols;  acc = accL;  e = (int)(e2 - E); }
    float v = vals[e]; int r = rows[e]; int cl = cols[e];
    const float4 x = *(const float4*)(ebs + (size_t)cl * D + c);
    float* o = acc + (size_t)r * D + c;
    unsafeAtomicAdd(o + 0, v * x.x);
    unsafeAtomicAdd(o + 1, v * x.y);
    unsafeAtomicAdd(o + 2, v * x.z);
    unsafeAtomicAdd(o + 3, v * x.w);
}

__global__ __launch_bounds__(256) void epilogue_kernel(
    const float* __restrict__ acc, const float* __restrict__ entity,
    const float* __restrict__ W_side, const float* __restrict__ W_dot,
    float* __restrict__ out, int n)
{
    int lane = threadIdx.x & 63;
    int wave = (blockIdx.x << 2) | (threadIdx.x >> 6);
    int row  = (wave << 6) + lane;
    bool valid = row < n;
    const float* accLI = acc;
    const float* accL  = acc + (size_t)n * D;
    float a[D], b[D];
    if (valid) {
        const float4* ap = (const float4*)(accLI  + (size_t)row * D);
        const float4* lp = (const float4*)(accL   + (size_t)row * D);
        const float4* ep = (const float4*)(entity + (size_t)row * D);
#pragma unroll
        for (int qq = 0; qq < 16; ++qq) {
            float4 av = ap[qq]; float4 lv = lp[qq]; float4 ev = ep[qq];
            a[4*qq+0] = av.x; a[4*qq+1] = av.y; a[4*qq+2] = av.z; a[4*qq+3] = av.w;
            b[4*qq+0] = lv.x * ev.x; b[4*qq+1] = lv.y * ev.y;
            b[4*qq+2] = lv.z * ev.z; b[4*qq+3] = lv.w * ev.w;
        }
    } else {
#pragma unroll
        for (int qq = 0; qq < D; ++qq) { a[qq] = 0.f; b[qq] = 0.f; }
    }
    float4* op = (float4*)(out + (size_t)row * D);
#pragma unroll 1
    for (int jc = 0; jc < 16; ++jc) {
        float a0 = 0.f, a1 = 0.f, a2 = 0.f, a3 = 0.f;
#pragma unroll
        for (int k = 0; k < D; ++k) {
            float4 w1 = *(const float4*)(W_side + (k << 6) + (jc << 2));
            float4 w2 = *(const float4*)(W_dot  + (k << 6) + (jc << 2));
            a0 += a[k] * w1.x + b[k] * w2.x;
            a1 += a[k] * w1.y + b[k] * w2.y;
            a2 += a[k] * w1.z + b[k] * w2.z;
            a3 += a[k] * w1.w + b[k] * w2.w;
        }
        float4 r;
        r.x = a0 > 0.f ? a0 : 0.2f * a0;
        r.y = a1 > 0.f ? a1 : 0.2f * a1;
        r.z = a2 > 0.f ? a2 : 0.2f * a2;
        r.w = a3 > 0.f ? a3 : 0.2f * a3;
        if (valid) op[jc] = r;
    }
}

extern "C" void kernel_launch(void* const* d_in, const int* in_sizes, int n_in,
                              void* d_out, int out_size, void* d_ws, size_t ws_size,
                              hipStream_t stream) {
    const float* ebs     = (const float*)d_in[0];
    const float* entity  = (const float*)d_in[1];
    const float* W_side  = (const float*)d_in[2];
    const float* W_dot   = (const float*)d_in[3];
    const float* LI_vals = (const float*)d_in[4];
    const float* L_vals  = (const float*)d_in[5];
    const int*   LI_rows = (const int*)d_in[6];
    const int*   LI_cols = (const int*)d_in[7];
    const int*   L_rows  = (const int*)d_in[8];
    const int*   L_cols  = (const int*)d_in[9];
    float* out = (float*)d_out;

    int E = in_sizes[4];
    int n = in_sizes[0] / D;
    int nbins = (n + BINROWS - 1) / BINROWS;

    size_t curBytes = (size_t)NSHARD * NBINS_MAX * CURSTRIDE * sizeof(int);   // 0.80 MB
    size_t segBytes = (size_t)NSHARD * NBINS_MAX * SUBCAP * sizeof(uint2);    // 25.7 MB
    size_t ebsBytes = (size_t)n * D * sizeof(unsigned short);                 // 12.8 MB
    size_t wfBytes  = (size_t)16 * 512 * sizeof(unsigned short);              // 16 KB
    size_t need = curBytes + segBytes + ebsBytes + wfBytes;

    if (ws_size >= need && nbins <= NBINS_MAX && n <= 131072) {
        int*            cursorP = (int*)d_ws;
        uint2*          seg     = (uint2*)((char*)d_ws + curBytes);
        unsigned short* ebs16   = (unsigned short*)((char*)d_ws + curBytes + segBytes);
        unsigned short* Wfrag   = (unsigned short*)((char*)d_ws + curBytes + segBytes + ebsBytes);

        hipMemsetAsync(cursorP, 0, curBytes, stream);

        int total4 = n * D / 4;
        convert_kernel<<<(total4 + 255) / 256, 256, 0, stream>>>(ebs, ebs16, total4);
        wfrag_kernel<<<4, 256, 0, stream>>>(W_side, W_dot, Wfrag);

        int xblocks = (2 * E + CHUNK - 1) / CHUNK;
        expand_bin_kernel<<<xblocks, 256, 0, stream>>>(
            LI_rows, LI_cols, LI_vals, L_rows, L_cols, L_vals,
            cursorP, seg, E, nbins);

        fused_kernel<<<nbins, 256, 0, stream>>>(
            seg, cursorP, ebs16, entity, Wfrag, out, n);
    } else {
        size_t accBytes = (size_t)2 * n * D * sizeof(float);
        float* acc   = (float*)d_ws;
        float* accLI = acc;
        float* accL  = accLI + (size_t)n * D;
        hipMemsetAsync(d_ws, 0, accBytes, stream);
        long long totalThreads = 2LL * E * 16;
        int sblocks = (int)((totalThreads + 255) / 256);
        scatter_kernel<<<sblocks, 256, 0, stream>>>(
            LI_vals, LI_rows, LI_cols, L_vals, L_rows, L_cols, ebs, accLI, accL, E);
        int nTiles = (n + 63) / 64;
        epilogue_kernel<<<(nTiles + 3) / 4, 256, 0, stream>>>(
            acc, entity, W_side, W_dot, out, n);
    }
}